// Round 1
// baseline (1205.235 us; speedup 1.0000x reference)
//
#include <hip/hip_runtime.h>
#include <math.h>

#define BATCH 4
#define CIN   1024
#define CB    256
#define HH    64
#define WW    64
#define PP    4096          // HH*WW
#define EPSV  1e-5f

// ---------------------------------------------------------------------------
// Generic fp32 GEMM: C[M,N] = A[M,K] x B[K,N], row-major. blockIdx.z = batch,
// B/C get per-batch offsets (A shared). BM=BN=128, BK=16, 256 thr, 8x8 micro.
// ---------------------------------------------------------------------------
__global__ __launch_bounds__(256)
void gemm_f32(const float* __restrict__ A, const float* __restrict__ Bg,
              float* __restrict__ Cg, int M, int N, int K) {
    const int b = blockIdx.z;
    const float* B = Bg + (size_t)b * K * N;
    float* C = Cg + (size_t)b * M * N;
    const int m0 = blockIdx.y * 128;
    const int n0 = blockIdx.x * 128;
    const int tid = threadIdx.x;
    const int ty = tid >> 4, tx = tid & 15;

    __shared__ __align__(16) float As[128 * 20];  // [m][k], stride 20
    __shared__ __align__(16) float Bs[128 * 20];  // [n][k], stride 20 (transposed)

    float acc[8][8];
#pragma unroll
    for (int i = 0; i < 8; i++)
#pragma unroll
        for (int j = 0; j < 8; j++) acc[i][j] = 0.f;

    for (int k0 = 0; k0 < K; k0 += 16) {
        // stage A: 128x16 = 512 float4
#pragma unroll
        for (int jj = 0; jj < 2; jj++) {
            int L = tid + 256 * jj;
            int m = L >> 2, k4 = (L & 3) << 2;
            float4 v = *(const float4*)(A + (size_t)(m0 + m) * K + k0 + k4);
            *(float4*)(&As[m * 20 + k4]) = v;
        }
        // stage B transposed: 16x128 = 512 float4
#pragma unroll
        for (int jj = 0; jj < 2; jj++) {
            int L = tid + 256 * jj;
            int k = L >> 5, n4 = (L & 31) << 2;
            float4 v = *(const float4*)(B + (size_t)(k0 + k) * N + n0 + n4);
            Bs[(n4 + 0) * 20 + k] = v.x;
            Bs[(n4 + 1) * 20 + k] = v.y;
            Bs[(n4 + 2) * 20 + k] = v.z;
            Bs[(n4 + 3) * 20 + k] = v.w;
        }
        __syncthreads();
#pragma unroll
        for (int kk4 = 0; kk4 < 4; kk4++) {
            float4 av[8], bv[8];
#pragma unroll
            for (int i = 0; i < 8; i++) av[i] = *(const float4*)(&As[(ty + 16 * i) * 20 + kk4 * 4]);
#pragma unroll
            for (int j = 0; j < 8; j++) bv[j] = *(const float4*)(&Bs[(tx + 16 * j) * 20 + kk4 * 4]);
#pragma unroll
            for (int i = 0; i < 8; i++)
#pragma unroll
                for (int j = 0; j < 8; j++) {
                    acc[i][j] += av[i].x * bv[j].x;
                    acc[i][j] += av[i].y * bv[j].y;
                    acc[i][j] += av[i].z * bv[j].z;
                    acc[i][j] += av[i].w * bv[j].w;
                }
        }
        __syncthreads();
    }
#pragma unroll
    for (int i = 0; i < 8; i++) {
        int m = m0 + ty + 16 * i;
#pragma unroll
        for (int j = 0; j < 8; j++) {
            C[(size_t)m * N + n0 + tx + 16 * j] = acc[i][j];
        }
    }
}

// ---------------------------------------------------------------------------
// GroupNorm stats: one block per (b, group). Writes {mean, rstd}.
// ---------------------------------------------------------------------------
__global__ __launch_bounds__(256)
void gn_stats(const float* __restrict__ src, float2* __restrict__ stats,
              int C, int Cpg) {
    int bg = blockIdx.x;
    int b = bg >> 5, g = bg & 31;                 // 32 groups always
    const float* base = src + ((size_t)b * C + (size_t)g * Cpg) * PP;
    int cnt = Cpg * PP;
    float s = 0.f, ss = 0.f;
    const float4* p4 = (const float4*)base;
    int n4 = cnt >> 2;
    for (int i = threadIdx.x; i < n4; i += 256) {
        float4 v = p4[i];
        s += v.x + v.y + v.z + v.w;
        ss += v.x * v.x + v.y * v.y + v.z * v.z + v.w * v.w;
    }
    for (int off = 32; off > 0; off >>= 1) {
        s += __shfl_down(s, off, 64);
        ss += __shfl_down(ss, off, 64);
    }
    __shared__ float rs[4], rss[4];
    int lane = threadIdx.x & 63, wid = threadIdx.x >> 6;
    if (lane == 0) { rs[wid] = s; rss[wid] = ss; }
    __syncthreads();
    if (threadIdx.x == 0) {
        float S = rs[0] + rs[1] + rs[2] + rs[3];
        float SS = rss[0] + rss[1] + rss[2] + rss[3];
        float mean = S / (float)cnt;
        float var = SS / (float)cnt - mean * mean;
        stats[bg] = make_float2(mean, rsqrtf(var + EPSV));
    }
}

// ---------------------------------------------------------------------------
// Apply GN + ReLU in place.
// ---------------------------------------------------------------------------
__global__ __launch_bounds__(256)
void gn_apply_relu(float* __restrict__ x, const float2* __restrict__ stats,
                   const float* __restrict__ sc, const float* __restrict__ bi,
                   int C, int Cpg) {
    long i = (long)blockIdx.x * 256 + threadIdx.x;
    long total4 = ((long)BATCH * C * PP) >> 2;
    if (i >= total4) return;
    long e = i << 2;
    int c = (int)((e >> 12) % C);
    int b = (int)(e / ((long)C * PP));
    float2 st = stats[b * 32 + c / Cpg];
    float a = st.y * sc[c];
    float bb = bi[c] - st.x * a;
    float4* p = (float4*)x;
    float4 v = p[i];
    v.x = fmaxf(v.x * a + bb, 0.f);
    v.y = fmaxf(v.y * a + bb, 0.f);
    v.z = fmaxf(v.z * a + bb, 0.f);
    v.w = fmaxf(v.w * a + bb, 0.f);
    p[i] = v;
}

// ---------------------------------------------------------------------------
// om init with bias.
// ---------------------------------------------------------------------------
__global__ __launch_bounds__(256)
void om_init(float* __restrict__ om, const float* __restrict__ boff) {
    int t = blockIdx.x * 256 + threadIdx.x;
    if (t < BATCH * 27 * PP) {
        int r = (t >> 12) % 27;
        om[t] = boff[r];
    }
}

// ---------------------------------------------------------------------------
// 3x3 offset conv, pad=1: om[b,r,p] += sum_c sum_k w_off[r,c,k]*out1[b,c,shift].
// Block: (rowgrp of 4 rows) x (channel chunk of 32) x batch; atomicAdd epilogue.
// ---------------------------------------------------------------------------
__global__ __launch_bounds__(256)
void conv_off_k(const float* __restrict__ out1, const float* __restrict__ w_off,
                float* __restrict__ om) {
    const int y0 = blockIdx.x * 4;
    const int c0 = blockIdx.y * 32;
    const int b = blockIdx.z;
    const int tid = threadIdx.x;
    const int tx = tid & 63, ty = tid >> 6;       // ty in [0,4)

    __shared__ __align__(16) float Aall[32 * 32 * 12];  // [c][r(pad32)][k(pad12)]
    __shared__ float strip[6 * 64];

    for (int e = tid; e < 32 * 384; e += 256) {
        int c = e / 384;
        int rk = e % 384;
        int r = rk / 12, k = rk % 12;
        float v = 0.f;
        if (r < 27 && k < 9) v = w_off[((size_t)r * CB + (c0 + c)) * 9 + k];
        Aall[e] = v;
    }

    float acc[8][4];
#pragma unroll
    for (int i = 0; i < 8; i++)
#pragma unroll
        for (int j = 0; j < 4; j++) acc[i][j] = 0.f;

    for (int c = 0; c < 32; c++) {
        __syncthreads();
        for (int e = tid; e < 384; e += 256) {
            int r = e >> 6, col = e & 63;
            int gy = y0 + r - 1;
            strip[e] = (gy >= 0 && gy < 64)
                ? out1[(((size_t)b * CB + c0 + c) << 12) + (gy << 6) + col] : 0.f;
        }
        __syncthreads();
        float v[6][3];
#pragma unroll
        for (int r = 0; r < 6; r++)
#pragma unroll
            for (int d = 0; d < 3; d++) {
                int col = tx + d - 1;
                v[r][d] = (col >= 0 && col < 64) ? strip[r * 64 + col] : 0.f;
            }
        const float* Ac = &Aall[c * 384];
#pragma unroll
        for (int i = 0; i < 8; i++) {
            int m = ty + 4 * i;
            float4 w0 = *(const float4*)(Ac + m * 12);
            float4 w1v = *(const float4*)(Ac + m * 12 + 4);
            float w8 = Ac[m * 12 + 8];
            float wk[9] = {w0.x, w0.y, w0.z, w0.w, w1v.x, w1v.y, w1v.z, w1v.w, w8};
#pragma unroll
            for (int kk = 0; kk < 9; kk++) {
                int dy = kk / 3, dx = kk % 3;
#pragma unroll
                for (int j = 0; j < 4; j++)
                    acc[i][j] += wk[kk] * v[j + dy][dx];
            }
        }
    }
#pragma unroll
    for (int i = 0; i < 8; i++) {
        int m = ty + 4 * i;
        if (m < 27) {
#pragma unroll
            for (int j = 0; j < 4; j++) {
                int p = ((y0 + j) << 6) + tx;
                atomicAdd(&om[((size_t)b * 27 + m) * PP + p], acc[i][j]);
            }
        }
    }
}

// ---------------------------------------------------------------------------
// Sampling prep: per (b,k,p) -> 4 corner indices + 4 weights (mask folded in).
// ---------------------------------------------------------------------------
__global__ __launch_bounds__(256)
void samp_prep(const float* __restrict__ om, float4* __restrict__ sw,
               int4* __restrict__ si) {
    int t = blockIdx.x * 256 + threadIdx.x;
    if (t >= BATCH * 9 * PP) return;
    int p = t & 4095;
    int k = (t >> 12) % 9;
    int b = t / (9 * PP);
    const float* ob = om + (size_t)b * 27 * PP;
    float offx = ob[(size_t)k * PP + p];
    float offy = ob[(size_t)(9 + k) * PP + p];
    float ms = 1.f / (1.f + expf(-ob[(size_t)(18 + k) * PP + p]));
    int y = p >> 6, x = p & 63;
    float py = (float)(y + k / 3 - 1) + offy;
    float px = (float)(x + (k % 3) - 1) + offx;
    float y0f = floorf(py), x0f = floorf(px);
    float wy1 = py - y0f, wx1 = px - x0f;
    int iy0 = (int)y0f, ix0 = (int)x0f;
    int iy1 = iy0 + 1, ix1 = ix0 + 1;
    bool vy0 = (iy0 >= 0 && iy0 < 64), vy1 = (iy1 >= 0 && iy1 < 64);
    bool vx0 = (ix0 >= 0 && ix0 < 64), vx1 = (ix1 >= 0 && ix1 < 64);
    int cy0 = min(max(iy0, 0), 63), cy1 = min(max(iy1, 0), 63);
    int cx0 = min(max(ix0, 0), 63), cx1 = min(max(ix1, 0), 63);
    float4 w;
    w.x = (vy0 && vx0) ? (1.f - wy1) * (1.f - wx1) * ms : 0.f;
    w.y = (vy0 && vx1) ? (1.f - wy1) * wx1 * ms : 0.f;
    w.z = (vy1 && vx0) ? wy1 * (1.f - wx1) * ms : 0.f;
    w.w = (vy1 && vx1) ? wy1 * wx1 * ms : 0.f;
    int4 id;
    id.x = (cy0 << 6) + cx0; id.y = (cy0 << 6) + cx1;
    id.z = (cy1 << 6) + cx0; id.w = (cy1 << 6) + cx1;
    sw[t] = w; si[t] = id;
}

// ---------------------------------------------------------------------------
// Deformable einsum GEMM: out2[b,o,p] += sum_{c,k} w2r[o,c*9+k] * S[c,k,p],
// S built on the fly in LDS from out1 + precomputed corner tables.
// BM=256 (full M), BN=64, K split in 2 chunks of 128 channels (atomic add).
// ---------------------------------------------------------------------------
__global__ __launch_bounds__(256)
void gemm2_deform(const float* __restrict__ out1, const float* __restrict__ w2,
                  const float4* __restrict__ sw, const int4* __restrict__ si,
                  float* __restrict__ out2) {
    const int p0 = blockIdx.x * 64;
    const int c0 = blockIdx.y * 128;   // channel chunk
    const int b = blockIdx.z;
    const int tid = threadIdx.x;
    const int ty = tid >> 4, tx = tid & 15;

    __shared__ __align__(16) float As[256 * 36];  // [m][kk], kk = cl*9+k
    __shared__ __align__(16) float Bs[64 * 36];   // [p][kk]
    __shared__ __align__(16) float swL[9 * 64 * 4];
    __shared__ __align__(16) int siL[9 * 64 * 4];

    for (int e = tid; e < 576; e += 256) {
        int k = e >> 6, p = e & 63;
        size_t gi = ((size_t)b * 9 + k) * PP + p0 + p;
        *(float4*)&swL[e * 4] = sw[gi];
        *(int4*)&siL[e * 4] = si[gi];
    }

    float acc[16][4];
#pragma unroll
    for (int i = 0; i < 16; i++)
#pragma unroll
        for (int j = 0; j < 4; j++) acc[i][j] = 0.f;

    for (int cg = 0; cg < 32; cg++) {
        __syncthreads();
        // stage A: 256 x 36 = 2304 float4
        int ckbase = (c0 + cg * 4) * 9;
#pragma unroll
        for (int jj = 0; jj < 9; jj++) {
            int L = tid + 256 * jj;
            int m = L / 9, k4 = (L % 9) * 4;
            float4 v = *(const float4*)(w2 + (size_t)m * 2304 + ckbase + k4);
            *(float4*)(&As[m * 36 + k4]) = v;
        }
        // stage B with fused bilinear sampling: 2304 elements
#pragma unroll
        for (int jj = 0; jj < 9; jj++) {
            int e = tid + 256 * jj;
            int p = e / 36, kk = e % 36;
            int cl = kk / 9, k = kk % 9;
            const float* row = out1 + ((size_t)b * CB + c0 + cg * 4 + cl) * PP;
            float4 wv = *(const float4*)&swL[(k * 64 + p) * 4];
            const int* iv = &siL[(k * 64 + p) * 4];
            float val = wv.x * row[iv[0]] + wv.y * row[iv[1]] +
                        wv.z * row[iv[2]] + wv.w * row[iv[3]];
            Bs[p * 36 + kk] = val;
        }
        __syncthreads();
#pragma unroll
        for (int k4 = 0; k4 < 9; k4++) {
            float4 bv[4];
#pragma unroll
            for (int j = 0; j < 4; j++) bv[j] = *(const float4*)(&Bs[(tx + 16 * j) * 36 + k4 * 4]);
#pragma unroll
            for (int i = 0; i < 16; i++) {
                float4 av = *(const float4*)(&As[(ty + 16 * i) * 36 + k4 * 4]);
#pragma unroll
                for (int j = 0; j < 4; j++) {
                    acc[i][j] += av.x * bv[j].x;
                    acc[i][j] += av.y * bv[j].y;
                    acc[i][j] += av.z * bv[j].z;
                    acc[i][j] += av.w * bv[j].w;
                }
            }
        }
    }
#pragma unroll
    for (int i = 0; i < 16; i++) {
        int o = ty + 16 * i;
#pragma unroll
        for (int j = 0; j < 4; j++) {
            atomicAdd(&out2[((size_t)b * CB + o) * PP + p0 + tx + 16 * j], acc[i][j]);
        }
    }
}

// ---------------------------------------------------------------------------
// Final: relu(gn3(d_out)*sc+bi + x) in place.
// ---------------------------------------------------------------------------
__global__ __launch_bounds__(256)
void final_k(float* __restrict__ dout, const float* __restrict__ x,
             const float2* __restrict__ stats, const float* __restrict__ sc,
             const float* __restrict__ bi) {
    long i = (long)blockIdx.x * 256 + threadIdx.x;
    long total4 = ((long)BATCH * CIN * PP) >> 2;
    if (i >= total4) return;
    long e = i << 2;
    int c = (int)((e >> 12) & 1023);
    int b = (int)(e >> 22);
    float2 st = stats[b * 32 + (c >> 5)];
    float a = st.y * sc[c];
    float bb = bi[c] - st.x * a;
    float4 v = ((float4*)dout)[i];
    float4 xv = ((const float4*)x)[i];
    v.x = fmaxf(v.x * a + bb + xv.x, 0.f);
    v.y = fmaxf(v.y * a + bb + xv.y, 0.f);
    v.z = fmaxf(v.z * a + bb + xv.z, 0.f);
    v.w = fmaxf(v.w * a + bb + xv.w, 0.f);
    ((float4*)dout)[i] = v;
}

// ---------------------------------------------------------------------------
extern "C" void kernel_launch(void* const* d_in, const int* in_sizes, int n_in,
                              void* d_out, int out_size, void* d_ws, size_t ws_size,
                              hipStream_t stream) {
    const float* x   = (const float*)d_in[0];
    const float* w1  = (const float*)d_in[1];
    const float* g1s = (const float*)d_in[2];
    const float* g1b = (const float*)d_in[3];
    const float* wof = (const float*)d_in[4];
    const float* bof = (const float*)d_in[5];
    const float* w2  = (const float*)d_in[6];
    const float* g2s = (const float*)d_in[7];
    const float* g2b = (const float*)d_in[8];
    const float* w3  = (const float*)d_in[9];
    const float* g3s = (const float*)d_in[10];
    const float* g3b = (const float*)d_in[11];
    float* out = (float*)d_out;

    float* ws = (float*)d_ws;
    float* out1 = ws;                          // 4,194,304 f
    float* out2 = ws + 4194304;                // 4,194,304 f
    float* om   = ws + 8388608;                //   442,368 f
    float4* sw  = (float4*)(ws + 8830976);     //   589,824 f
    int4*  si   = (int4*)(ws + 9420800);       //   589,824 i
    float2* st1 = (float2*)(ws + 10010624);
    float2* st2 = st1 + 128;
    float2* st3 = st2 + 128;

    // conv1 (1x1): out1 = w1 @ x
    gemm_f32<<<dim3(32, 2, 4), 256, 0, stream>>>(w1, x, out1, 256, 4096, 1024);
    // GN1 + ReLU in place
    gn_stats<<<128, 256, 0, stream>>>(out1, st1, 256, 8);
    gn_apply_relu<<<4096, 256, 0, stream>>>(out1, st1, g1s, g1b, 256, 8);
    // offset conv (3x3, pad 1) + bias
    om_init<<<1728, 256, 0, stream>>>(om, bof);
    conv_off_k<<<dim3(16, 8, 4), 256, 0, stream>>>(out1, wof, om);
    // bilinear corner/weight tables
    samp_prep<<<576, 256, 0, stream>>>(om, sw, si);
    // deformable einsum
    hipMemsetAsync(out2, 0, (size_t)4194304 * sizeof(float), stream);
    gemm2_deform<<<dim3(64, 2, 4), 256, 0, stream>>>(out1, w2, sw, si, out2);
    // GN2 + ReLU
    gn_stats<<<128, 256, 0, stream>>>(out2, st2, 256, 8);
    gn_apply_relu<<<4096, 256, 0, stream>>>(out2, st2, g2s, g2b, 256, 8);
    // conv3 (1x1) -> d_out as scratch
    gemm_f32<<<dim3(32, 8, 4), 256, 0, stream>>>(w3, out2, out, 1024, 4096, 256);
    // GN3 + residual + ReLU in place
    gn_stats<<<128, 256, 0, stream>>>(out, st3, 1024, 32);
    final_k<<<16384, 256, 0, stream>>>(out, x, st3, g3s, g3b);
}

// Round 3
// 712.790 us; speedup vs baseline: 1.6909x; 1.6909x over previous
//
#include <hip/hip_runtime.h>
#include <math.h>

#define BATCH 4
#define CIN   1024
#define CB    256
#define HH    64
#define WW    64
#define PP    4096          // HH*WW
#define EPSV  1e-5f

using shortx8 = __attribute__((ext_vector_type(8))) short;
using floatx4 = __attribute__((ext_vector_type(4))) float;
using intx4   = __attribute__((ext_vector_type(4))) int;

static __device__ inline unsigned short f2bf(float f) {
    unsigned int u = __float_as_uint(f);
    u += 0x7fffu + ((u >> 16) & 1u);      // RNE
    return (unsigned short)(u >> 16);
}

// ---------------------------------------------------------------------------
// Generic fp32 GEMM (conv1 / conv3). Unchanged from R1 (known correct).
// ---------------------------------------------------------------------------
__global__ __launch_bounds__(256)
void gemm_f32(const float* __restrict__ A, const float* __restrict__ Bg,
              float* __restrict__ Cg, int M, int N, int K) {
    const int b = blockIdx.z;
    const float* B = Bg + (size_t)b * K * N;
    float* C = Cg + (size_t)b * M * N;
    const int m0 = blockIdx.y * 128;
    const int n0 = blockIdx.x * 128;
    const int tid = threadIdx.x;
    const int ty = tid >> 4, tx = tid & 15;

    __shared__ __align__(16) float As[128 * 20];
    __shared__ __align__(16) float Bs[128 * 20];

    float acc[8][8];
#pragma unroll
    for (int i = 0; i < 8; i++)
#pragma unroll
        for (int j = 0; j < 8; j++) acc[i][j] = 0.f;

    for (int k0 = 0; k0 < K; k0 += 16) {
#pragma unroll
        for (int jj = 0; jj < 2; jj++) {
            int L = tid + 256 * jj;
            int m = L >> 2, k4 = (L & 3) << 2;
            float4 v = *(const float4*)(A + (size_t)(m0 + m) * K + k0 + k4);
            *(float4*)(&As[m * 20 + k4]) = v;
        }
#pragma unroll
        for (int jj = 0; jj < 2; jj++) {
            int L = tid + 256 * jj;
            int k = L >> 5, n4 = (L & 31) << 2;
            float4 v = *(const float4*)(B + (size_t)(k0 + k) * N + n0 + n4);
            Bs[(n4 + 0) * 20 + k] = v.x;
            Bs[(n4 + 1) * 20 + k] = v.y;
            Bs[(n4 + 2) * 20 + k] = v.z;
            Bs[(n4 + 3) * 20 + k] = v.w;
        }
        __syncthreads();
#pragma unroll
        for (int kk4 = 0; kk4 < 4; kk4++) {
            float4 av[8], bv[8];
#pragma unroll
            for (int i = 0; i < 8; i++) av[i] = *(const float4*)(&As[(ty + 16 * i) * 20 + kk4 * 4]);
#pragma unroll
            for (int j = 0; j < 8; j++) bv[j] = *(const float4*)(&Bs[(tx + 16 * j) * 20 + kk4 * 4]);
#pragma unroll
            for (int i = 0; i < 8; i++)
#pragma unroll
                for (int j = 0; j < 8; j++) {
                    acc[i][j] += av[i].x * bv[j].x;
                    acc[i][j] += av[i].y * bv[j].y;
                    acc[i][j] += av[i].z * bv[j].z;
                    acc[i][j] += av[i].w * bv[j].w;
                }
        }
        __syncthreads();
    }
#pragma unroll
    for (int i = 0; i < 8; i++) {
        int m = m0 + ty + 16 * i;
#pragma unroll
        for (int j = 0; j < 8; j++) {
            C[(size_t)m * N + n0 + tx + 16 * j] = acc[i][j];
        }
    }
}

// ---------------------------------------------------------------------------
// GroupNorm stats
// ---------------------------------------------------------------------------
__global__ __launch_bounds__(256)
void gn_stats(const float* __restrict__ src, float2* __restrict__ stats,
              int C, int Cpg) {
    int bg = blockIdx.x;
    int b = bg >> 5, g = bg & 31;
    const float* base = src + ((size_t)b * C + (size_t)g * Cpg) * PP;
    int cnt = Cpg * PP;
    float s = 0.f, ss = 0.f;
    const float4* p4 = (const float4*)base;
    int n4 = cnt >> 2;
    for (int i = threadIdx.x; i < n4; i += 256) {
        float4 v = p4[i];
        s += v.x + v.y + v.z + v.w;
        ss += v.x * v.x + v.y * v.y + v.z * v.z + v.w * v.w;
    }
    for (int off = 32; off > 0; off >>= 1) {
        s += __shfl_down(s, off, 64);
        ss += __shfl_down(ss, off, 64);
    }
    __shared__ float rs[4], rss[4];
    int lane = threadIdx.x & 63, wid = threadIdx.x >> 6;
    if (lane == 0) { rs[wid] = s; rss[wid] = ss; }
    __syncthreads();
    if (threadIdx.x == 0) {
        float S = rs[0] + rs[1] + rs[2] + rs[3];
        float SS = rss[0] + rss[1] + rss[2] + rss[3];
        float mean = S / (float)cnt;
        float var = SS / (float)cnt - mean * mean;
        stats[bg] = make_float2(mean, rsqrtf(var + EPSV));
    }
}

// ---------------------------------------------------------------------------
// GN + ReLU apply (in place)
// ---------------------------------------------------------------------------
__global__ __launch_bounds__(256)
void gn_apply_relu(float* __restrict__ x, const float2* __restrict__ stats,
                   const float* __restrict__ sc, const float* __restrict__ bi,
                   int C, int Cpg) {
    long i = (long)blockIdx.x * 256 + threadIdx.x;
    long total4 = ((long)BATCH * C * PP) >> 2;
    if (i >= total4) return;
    long e = i << 2;
    int c = (int)((e >> 12) % C);
    int b = (int)(e / ((long)C * PP));
    float2 st = stats[b * 32 + c / Cpg];
    float a = st.y * sc[c];
    float bb = bi[c] - st.x * a;
    float4* p = (float4*)x;
    float4 v = p[i];
    v.x = fmaxf(v.x * a + bb, 0.f);
    v.y = fmaxf(v.y * a + bb, 0.f);
    v.z = fmaxf(v.z * a + bb, 0.f);
    v.w = fmaxf(v.w * a + bb, 0.f);
    p[i] = v;
}

// ---------------------------------------------------------------------------
__global__ __launch_bounds__(256)
void om_init(float* __restrict__ om, const float* __restrict__ boff) {
    int t = blockIdx.x * 256 + threadIdx.x;
    if (t < BATCH * 27 * PP) {
        int r = (t >> 12) % 27;
        om[t] = boff[r];
    }
}

// ---------------------------------------------------------------------------
// 3x3 offset conv (unchanged)
// ---------------------------------------------------------------------------
__global__ __launch_bounds__(256)
void conv_off_k(const float* __restrict__ out1, const float* __restrict__ w_off,
                float* __restrict__ om) {
    const int y0 = blockIdx.x * 4;
    const int c0 = blockIdx.y * 32;
    const int b = blockIdx.z;
    const int tid = threadIdx.x;
    const int tx = tid & 63, ty = tid >> 6;

    __shared__ __align__(16) float Aall[32 * 32 * 12];
    __shared__ float strip[6 * 64];

    for (int e = tid; e < 32 * 384; e += 256) {
        int c = e / 384;
        int rk = e % 384;
        int r = rk / 12, k = rk % 12;
        float v = 0.f;
        if (r < 27 && k < 9) v = w_off[((size_t)r * CB + (c0 + c)) * 9 + k];
        Aall[e] = v;
    }

    float acc[8][4];
#pragma unroll
    for (int i = 0; i < 8; i++)
#pragma unroll
        for (int j = 0; j < 4; j++) acc[i][j] = 0.f;

    for (int c = 0; c < 32; c++) {
        __syncthreads();
        for (int e = tid; e < 384; e += 256) {
            int r = e >> 6, col = e & 63;
            int gy = y0 + r - 1;
            strip[e] = (gy >= 0 && gy < 64)
                ? out1[(((size_t)b * CB + c0 + c) << 12) + (gy << 6) + col] : 0.f;
        }
        __syncthreads();
        float v[6][3];
#pragma unroll
        for (int r = 0; r < 6; r++)
#pragma unroll
            for (int d = 0; d < 3; d++) {
                int col = tx + d - 1;
                v[r][d] = (col >= 0 && col < 64) ? strip[r * 64 + col] : 0.f;
            }
        const float* Ac = &Aall[c * 384];
#pragma unroll
        for (int i = 0; i < 8; i++) {
            int m = ty + 4 * i;
            float4 w0 = *(const float4*)(Ac + m * 12);
            float4 w1v = *(const float4*)(Ac + m * 12 + 4);
            float w8 = Ac[m * 12 + 8];
            float wk[9] = {w0.x, w0.y, w0.z, w0.w, w1v.x, w1v.y, w1v.z, w1v.w, w8};
#pragma unroll
            for (int kk = 0; kk < 9; kk++) {
                int dy = kk / 3, dx = kk % 3;
#pragma unroll
                for (int j = 0; j < 4; j++)
                    acc[i][j] += wk[kk] * v[j + dy][dx];
            }
        }
    }
#pragma unroll
    for (int i = 0; i < 8; i++) {
        int m = ty + 4 * i;
        if (m < 27) {
#pragma unroll
            for (int j = 0; j < 4; j++) {
                int p = ((y0 + j) << 6) + tx;
                atomicAdd(&om[((size_t)b * 27 + m) * PP + p], acc[i][j]);
            }
        }
    }
}

// ---------------------------------------------------------------------------
// Sampling prep (unchanged)
// ---------------------------------------------------------------------------
__global__ __launch_bounds__(256)
void samp_prep(const float* __restrict__ om, float4* __restrict__ sw,
               int4* __restrict__ si) {
    int t = blockIdx.x * 256 + threadIdx.x;
    if (t >= BATCH * 9 * PP) return;
    int p = t & 4095;
    int k = (t >> 12) % 9;
    int b = t / (9 * PP);
    const float* ob = om + (size_t)b * 27 * PP;
    float offx = ob[(size_t)k * PP + p];
    float offy = ob[(size_t)(9 + k) * PP + p];
    float ms = 1.f / (1.f + expf(-ob[(size_t)(18 + k) * PP + p]));
    int y = p >> 6, x = p & 63;
    float py = (float)(y + k / 3 - 1) + offy;
    float px = (float)(x + (k % 3) - 1) + offx;
    float y0f = floorf(py), x0f = floorf(px);
    float wy1 = py - y0f, wx1 = px - x0f;
    int iy0 = (int)y0f, ix0 = (int)x0f;
    int iy1 = iy0 + 1, ix1 = ix0 + 1;
    bool vy0 = (iy0 >= 0 && iy0 < 64), vy1 = (iy1 >= 0 && iy1 < 64);
    bool vx0 = (ix0 >= 0 && ix0 < 64), vx1 = (ix1 >= 0 && ix1 < 64);
    int cy0 = min(max(iy0, 0), 63), cy1 = min(max(iy1, 0), 63);
    int cx0 = min(max(ix0, 0), 63), cx1 = min(max(ix1, 0), 63);
    float4 w;
    w.x = (vy0 && vx0) ? (1.f - wy1) * (1.f - wx1) * ms : 0.f;
    w.y = (vy0 && vx1) ? (1.f - wy1) * wx1 * ms : 0.f;
    w.z = (vy1 && vx0) ? wy1 * (1.f - wx1) * ms : 0.f;
    w.w = (vy1 && vx1) ? wy1 * wx1 * ms : 0.f;
    int4 id;
    id.x = (cy0 << 6) + cx0; id.y = (cy0 << 6) + cx1;
    id.z = (cy1 << 6) + cx0; id.w = (cy1 << 6) + cx1;
    sw[t] = w; si[t] = id;
}

// ---------------------------------------------------------------------------
// w2 fp32 [o][c][tap] -> bf16, K reordered: w2bf[o][tap*256 + c]
// ---------------------------------------------------------------------------
__global__ __launch_bounds__(256)
void w2conv(const float* __restrict__ w2, unsigned short* __restrict__ w2bf) {
    int t = blockIdx.x * 256 + threadIdx.x;
    if (t >= 256 * 2304) return;
    int o = t / 2304;
    int r = t - o * 2304;
    int tap = r >> 8, c = r & 255;
    w2bf[t] = f2bf(w2[((size_t)o * 256 + c) * 9 + tap]);
}

// ---------------------------------------------------------------------------
// Deformable einsum with bf16 MFMA.
// C[256 o][4096 p] per batch; K' = tap*256 + c (2304). BM=256(full), BN=64.
// 512 threads = 8 waves; wave w -> rows [32w,32w+32) via 2x4 tiles of
// mfma_f32_16x16x32_bf16. B tile built on the fly (bilinear gather, bf16).
// Grid: 64 p-tiles x 4 batches = 256 blocks (1/CU), no atomics.
// R3 fix: A staging now fills the FULL 32-channel row (2x float4 per thread,
// 32B each = 16KB total); R2 only staged half -> stale-LDS garbage.
// ---------------------------------------------------------------------------
__global__ __launch_bounds__(512)
void gemm2_mfma(const float* __restrict__ out1, const unsigned short* __restrict__ w2bf,
                const float4* __restrict__ sw, const int4* __restrict__ si,
                float* __restrict__ out2) {
    const int p0 = blockIdx.x * 64;
    const int b = blockIdx.z;
    const int tid = threadIdx.x;
    const int lane = tid & 63;
    const int wid = tid >> 6;          // 0..7
    const int l15 = lane & 15;
    const int quad = lane >> 4;        // 0..3

    __shared__ __align__(16) unsigned short As[256 * 40];  // [o][k] stride 40
    __shared__ __align__(16) unsigned short Bs[64 * 40];   // [p][k] stride 40
    __shared__ __align__(16) float swL[9 * 64 * 4];
    __shared__ __align__(16) int   siL[9 * 64 * 4];

    // stage bilinear tables for this (b, p-tile)
    for (int e = tid; e < 576; e += 512) {
        int k = e >> 6, p = e & 63;
        size_t gi = ((size_t)b * 9 + k) * PP + p0 + p;
        *(floatx4*)&swL[e * 4] = *(const floatx4*)&sw[gi];
        *(intx4*)&siL[e * 4] = *(const intx4*)&si[gi];
    }

    floatx4 acc[2][4];
#pragma unroll
    for (int i = 0; i < 2; i++)
#pragma unroll
        for (int j = 0; j < 4; j++) acc[i][j] = (floatx4){0.f, 0.f, 0.f, 0.f};

    // build-phase thread mapping: p = tid&63, cq = tid>>6 (4 channels each)
    const int bp = tid & 63;
    const int bcq = tid >> 6;
    // A-staging mapping: row = tid>>1 (0..255), half = tid&1 (16 bf16 each)
    const int so = tid >> 1;
    const int sh = tid & 1;

    __syncthreads();   // tables ready

    const int mbase = wid * 32;

    for (int tap = 0; tap < 9; tap++) {
        floatx4 wv = *(const floatx4*)&swL[(tap * 64 + bp) * 4];
        intx4 iv = *(const intx4*)&siL[(tap * 64 + bp) * 4];
        for (int cc = 0; cc < 8; cc++) {
            const int c0 = cc * 32;
            // ---- stage A tile: w2bf[o][tap*256 + c0 .. c0+32) -> As[o][0..32)
            // each of 2 threads/row stages 16 bf16 (two float4 = 32B)
            {
                const unsigned short* gsrc =
                    w2bf + (size_t)so * 2304 + tap * 256 + c0 + sh * 16;
                float4 v0 = *(const float4*)gsrc;
                float4 v1 = *(const float4*)(gsrc + 8);
                *(float4*)((char*)As + so * 80 + sh * 32) = v0;
                *(float4*)((char*)As + so * 80 + sh * 32 + 16) = v1;
            }
            // ---- build B tile: 4 channels for pixel bp
            {
                const float* rowb = out1 + (((size_t)b * CB + c0 + bcq * 4) << 12);
                unsigned short bv[4];
#pragma unroll
                for (int s = 0; s < 4; s++) {
                    const float* row = rowb + ((size_t)s << 12);
                    float v = wv[0] * row[iv[0]] + wv[1] * row[iv[1]] +
                              wv[2] * row[iv[2]] + wv[3] * row[iv[3]];
                    bv[s] = f2bf(v);
                }
                *(ushort4*)((char*)Bs + bp * 80 + bcq * 8) =
                    make_ushort4(bv[0], bv[1], bv[2], bv[3]);
            }
            __syncthreads();
            // ---- MFMA phase
            shortx8 af[2], bf[4];
#pragma unroll
            for (int i = 0; i < 2; i++)
                af[i] = *(const shortx8*)((const char*)As +
                        (mbase + 16 * i + l15) * 80 + quad * 16);
#pragma unroll
            for (int j = 0; j < 4; j++)
                bf[j] = *(const shortx8*)((const char*)Bs +
                        (16 * j + l15) * 80 + quad * 16);
#pragma unroll
            for (int i = 0; i < 2; i++)
#pragma unroll
                for (int j = 0; j < 4; j++)
                    acc[i][j] = __builtin_amdgcn_mfma_f32_16x16x32_bf16(
                        af[i], bf[j], acc[i][j], 0, 0, 0);
            __syncthreads();
        }
    }

    // epilogue: D col = lane&15, row = quad*4+reg
#pragma unroll
    for (int i = 0; i < 2; i++) {
#pragma unroll
        for (int r = 0; r < 4; r++) {
            int row = mbase + 16 * i + quad * 4 + r;
            float* dst = out2 + (((size_t)b * CB + row) << 12) + p0 + l15;
#pragma unroll
            for (int j = 0; j < 4; j++)
                dst[16 * j] = acc[i][j][r];
        }
    }
}

// ---------------------------------------------------------------------------
// Final: relu(gn3(d_out)*sc+bi + x) in place.
// ---------------------------------------------------------------------------
__global__ __launch_bounds__(256)
void final_k(float* __restrict__ dout, const float* __restrict__ x,
             const float2* __restrict__ stats, const float* __restrict__ sc,
             const float* __restrict__ bi) {
    long i = (long)blockIdx.x * 256 + threadIdx.x;
    long total4 = ((long)BATCH * CIN * PP) >> 2;
    if (i >= total4) return;
    long e = i << 2;
    int c = (int)((e >> 12) & 1023);
    int b = (int)(e >> 22);
    float2 st = stats[b * 32 + (c >> 5)];
    float a = st.y * sc[c];
    float bb = bi[c] - st.x * a;
    float4 v = ((float4*)dout)[i];
    float4 xv = ((const float4*)x)[i];
    v.x = fmaxf(v.x * a + bb + xv.x, 0.f);
    v.y = fmaxf(v.y * a + bb + xv.y, 0.f);
    v.z = fmaxf(v.z * a + bb + xv.z, 0.f);
    v.w = fmaxf(v.w * a + bb + xv.w, 0.f);
    ((float4*)dout)[i] = v;
}

// ---------------------------------------------------------------------------
extern "C" void kernel_launch(void* const* d_in, const int* in_sizes, int n_in,
                              void* d_out, int out_size, void* d_ws, size_t ws_size,
                              hipStream_t stream) {
    const float* x   = (const float*)d_in[0];
    const float* w1  = (const float*)d_in[1];
    const float* g1s = (const float*)d_in[2];
    const float* g1b = (const float*)d_in[3];
    const float* wof = (const float*)d_in[4];
    const float* bof = (const float*)d_in[5];
    const float* w2  = (const float*)d_in[6];
    const float* g2s = (const float*)d_in[7];
    const float* g2b = (const float*)d_in[8];
    const float* w3  = (const float*)d_in[9];
    const float* g3s = (const float*)d_in[10];
    const float* g3b = (const float*)d_in[11];
    float* out = (float*)d_out;

    float* ws = (float*)d_ws;
    float* out1 = ws;                          // 4,194,304 f
    float* out2 = ws + 4194304;                // 4,194,304 f
    float* om   = ws + 8388608;                //   442,368 f (reused as w2bf)
    float4* sw  = (float4*)(ws + 8830976);     //   589,824 f
    int4*  si   = (int4*)(ws + 9420800);       //   589,824 i
    float2* st1 = (float2*)(ws + 10010624);
    float2* st2 = st1 + 128;
    float2* st3 = st2 + 128;
    unsigned short* w2bf = (unsigned short*)om; // aliases om (dead after samp_prep)

    // conv1 (1x1): out1 = w1 @ x
    gemm_f32<<<dim3(32, 2, 4), 256, 0, stream>>>(w1, x, out1, 256, 4096, 1024);
    gn_stats<<<128, 256, 0, stream>>>(out1, st1, 256, 8);
    gn_apply_relu<<<4096, 256, 0, stream>>>(out1, st1, g1s, g1b, 256, 8);
    // offset conv (3x3, pad 1) + bias
    om_init<<<1728, 256, 0, stream>>>(om, bof);
    conv_off_k<<<dim3(16, 8, 4), 256, 0, stream>>>(out1, wof, om);
    samp_prep<<<576, 256, 0, stream>>>(om, sw, si);
    // w2 -> bf16 (K reordered) into om's storage (om now dead)
    w2conv<<<2304, 256, 0, stream>>>(w2, w2bf);
    // deformable einsum, bf16 MFMA
    gemm2_mfma<<<dim3(64, 1, 4), 512, 0, stream>>>(out1, w2bf, sw, si, out2);
    // GN2 + ReLU
    gn_stats<<<128, 256, 0, stream>>>(out2, st2, 256, 8);
    gn_apply_relu<<<4096, 256, 0, stream>>>(out2, st2, g2s, g2b, 256, 8);
    // conv3 (1x1) -> d_out as scratch
    gemm_f32<<<dim3(32, 8, 4), 256, 0, stream>>>(w3, out2, out, 1024, 4096, 256);
    gn_stats<<<128, 256, 0, stream>>>(out, st3, 1024, 32);
    final_k<<<16384, 256, 0, stream>>>(out, x, st3, g3s, g3b);
}

// Round 4
// 501.691 us; speedup vs baseline: 2.4023x; 1.4208x over previous
//
#include <hip/hip_runtime.h>
#include <math.h>

#define BATCH 4
#define CIN   1024
#define CB    256
#define HH    64
#define WW    64
#define PP    4096          // HH*WW
#define EPSV  1e-5f

using shortx8 = __attribute__((ext_vector_type(8))) short;
using floatx4 = __attribute__((ext_vector_type(4))) float;
using intx4   = __attribute__((ext_vector_type(4))) int;

static __device__ inline unsigned short f2bf(float f) {
    unsigned int u = __float_as_uint(f);
    u += 0x7fffu + ((u >> 16) & 1u);      // RNE
    return (unsigned short)(u >> 16);
}

// ---------------------------------------------------------------------------
// bf16 MFMA GEMM: C[M,N] fp32 = A[M,K]bf16 @ B^T[N,K]bf16. A shared across
// batch, BT/C per-batch (blockIdx.z). 128x128 tile, BK=32, 256 thr = 4 waves,
// wave w -> rows [32w,32w+32), 2x8 tiles of mfma_f32_16x16x32_bf16.
// LDS rows stride 40 shorts (80B) -> <=2-way banks (free).
// ---------------------------------------------------------------------------
__global__ __launch_bounds__(256)
void gemm_bf16(const unsigned short* __restrict__ A,
               const unsigned short* __restrict__ BTg,
               float* __restrict__ Cg, int M, int N, int K) {
    const int b = blockIdx.z;
    const unsigned short* BT = BTg + (size_t)b * N * K;
    float* C = Cg + (size_t)b * M * N;
    const int m0 = blockIdx.y * 128;
    const int n0 = blockIdx.x * 128;
    const int tid = threadIdx.x;
    const int lane = tid & 63;
    const int wid = tid >> 6;
    const int l15 = lane & 15;
    const int quad = lane >> 4;

    __shared__ __align__(16) unsigned short As[128 * 40];
    __shared__ __align__(16) unsigned short Bs[128 * 40];

    floatx4 acc[2][8];
#pragma unroll
    for (int i = 0; i < 2; i++)
#pragma unroll
        for (int j = 0; j < 8; j++) acc[i][j] = (floatx4){0.f, 0.f, 0.f, 0.f};

    const int row = tid >> 1;      // 0..127
    const int half = tid & 1;      // 16 shorts each

    for (int k0 = 0; k0 < K; k0 += 32) {
        const unsigned short* ga = A + (size_t)(m0 + row) * K + k0 + half * 16;
        const unsigned short* gb = BT + (size_t)(n0 + row) * K + k0 + half * 16;
        float4 a0 = *(const float4*)ga;
        float4 a1 = *(const float4*)(ga + 8);
        float4 b0 = *(const float4*)gb;
        float4 b1 = *(const float4*)(gb + 8);
        __syncthreads();
        *(float4*)((char*)As + row * 80 + half * 32) = a0;
        *(float4*)((char*)As + row * 80 + half * 32 + 16) = a1;
        *(float4*)((char*)Bs + row * 80 + half * 32) = b0;
        *(float4*)((char*)Bs + row * 80 + half * 32 + 16) = b1;
        __syncthreads();
        shortx8 af[2], bf[8];
#pragma unroll
        for (int i = 0; i < 2; i++)
            af[i] = *(const shortx8*)((const char*)As +
                    (wid * 32 + 16 * i + l15) * 80 + quad * 16);
#pragma unroll
        for (int j = 0; j < 8; j++)
            bf[j] = *(const shortx8*)((const char*)Bs +
                    (16 * j + l15) * 80 + quad * 16);
#pragma unroll
        for (int i = 0; i < 2; i++)
#pragma unroll
            for (int j = 0; j < 8; j++)
                acc[i][j] = __builtin_amdgcn_mfma_f32_16x16x32_bf16(
                    af[i], bf[j], acc[i][j], 0, 0, 0);
    }

    // D: col = lane&15, row = quad*4 + reg
#pragma unroll
    for (int i = 0; i < 2; i++) {
#pragma unroll
        for (int r = 0; r < 4; r++) {
            int m = m0 + wid * 32 + 16 * i + quad * 4 + r;
            float* dst = C + (size_t)m * N + n0 + l15;
#pragma unroll
            for (int j = 0; j < 8; j++)
                dst[16 * j] = acc[i][j][r];
        }
    }
}

// ---------------------------------------------------------------------------
// Tiled transpose + fp32->bf16: src [b][C][P] -> dst [b][P][C]
// ---------------------------------------------------------------------------
__global__ __launch_bounds__(256)
void transp_bf16(const float* __restrict__ src, unsigned short* __restrict__ dst,
                 int C, int P) {
    const int p0 = blockIdx.x * 64;
    const int c0 = blockIdx.y * 64;
    const int b = blockIdx.z;
    __shared__ unsigned short t[64][72];
    const float* s = src + ((size_t)b * C + c0) * P + p0;
    for (int e = threadIdx.x; e < 4096; e += 256) {
        int r = e >> 6, col = e & 63;
        t[r][col] = f2bf(s[(size_t)r * P + col]);
    }
    __syncthreads();
    unsigned short* d = dst + ((size_t)b * P + p0) * C + c0;
    for (int u = threadIdx.x; u < 512; u += 256) {
        int pr = u >> 3, c8 = (u & 7) * 8;
        ushort4 v0, v1;
        v0.x = t[c8 + 0][pr]; v0.y = t[c8 + 1][pr];
        v0.z = t[c8 + 2][pr]; v0.w = t[c8 + 3][pr];
        v1.x = t[c8 + 4][pr]; v1.y = t[c8 + 5][pr];
        v1.z = t[c8 + 6][pr]; v1.w = t[c8 + 7][pr];
        *(ushort4*)&d[(size_t)pr * C + c8] = v0;
        *(ushort4*)&d[(size_t)pr * C + c8 + 4] = v1;
    }
}

// ---------------------------------------------------------------------------
// GN2 apply + ReLU + transpose-convert: out2 fp32 [b][256][P] -> bf16 [b][P][256]
// ---------------------------------------------------------------------------
__global__ __launch_bounds__(256)
void gn2t(const float* __restrict__ src, const float2* __restrict__ st,
          const float* __restrict__ sc, const float* __restrict__ bi,
          unsigned short* __restrict__ dst) {
    const int p0 = blockIdx.x * 64;
    const int c0 = blockIdx.y * 64;
    const int b = blockIdx.z;
    __shared__ unsigned short t[64][72];
    const float* s = src + ((size_t)b * CB + c0) * PP + p0;
    for (int e = threadIdx.x; e < 4096; e += 256) {
        int r = e >> 6, col = e & 63;
        int c = c0 + r;
        float2 m = st[b * 32 + (c >> 3)];       // Cpg = 8
        float a = m.y * sc[c];
        float bb = bi[c] - m.x * a;
        t[r][col] = f2bf(fmaxf(s[(size_t)r * PP + col] * a + bb, 0.f));
    }
    __syncthreads();
    unsigned short* d = dst + ((size_t)b * PP + p0) * CB + c0;
    for (int u = threadIdx.x; u < 512; u += 256) {
        int pr = u >> 3, c8 = (u & 7) * 8;
        ushort4 v0, v1;
        v0.x = t[c8 + 0][pr]; v0.y = t[c8 + 1][pr];
        v0.z = t[c8 + 2][pr]; v0.w = t[c8 + 3][pr];
        v1.x = t[c8 + 4][pr]; v1.y = t[c8 + 5][pr];
        v1.z = t[c8 + 6][pr]; v1.w = t[c8 + 7][pr];
        *(ushort4*)&d[(size_t)pr * CB + c8] = v0;
        *(ushort4*)&d[(size_t)pr * CB + c8 + 4] = v1;
    }
}

// ---------------------------------------------------------------------------
// plain fp32 -> bf16 cast
// ---------------------------------------------------------------------------
__global__ __launch_bounds__(256)
void cvt_bf16(const float* __restrict__ s, unsigned short* __restrict__ d, int n) {
    int i = blockIdx.x * 256 + threadIdx.x;
    if (i < n) d[i] = f2bf(s[i]);
}

// ---------------------------------------------------------------------------
// GroupNorm stats
// ---------------------------------------------------------------------------
__global__ __launch_bounds__(256)
void gn_stats(const float* __restrict__ src, float2* __restrict__ stats,
              int C, int Cpg) {
    int bg = blockIdx.x;
    int b = bg >> 5, g = bg & 31;
    const float* base = src + ((size_t)b * C + (size_t)g * Cpg) * PP;
    int cnt = Cpg * PP;
    float s = 0.f, ss = 0.f;
    const float4* p4 = (const float4*)base;
    int n4 = cnt >> 2;
    for (int i = threadIdx.x; i < n4; i += 256) {
        float4 v = p4[i];
        s += v.x + v.y + v.z + v.w;
        ss += v.x * v.x + v.y * v.y + v.z * v.z + v.w * v.w;
    }
    for (int off = 32; off > 0; off >>= 1) {
        s += __shfl_down(s, off, 64);
        ss += __shfl_down(ss, off, 64);
    }
    __shared__ float rs[4], rss[4];
    int lane = threadIdx.x & 63, wid = threadIdx.x >> 6;
    if (lane == 0) { rs[wid] = s; rss[wid] = ss; }
    __syncthreads();
    if (threadIdx.x == 0) {
        float S = rs[0] + rs[1] + rs[2] + rs[3];
        float SS = rss[0] + rss[1] + rss[2] + rss[3];
        float mean = S / (float)cnt;
        float var = SS / (float)cnt - mean * mean;
        stats[bg] = make_float2(mean, rsqrtf(var + EPSV));
    }
}

// ---------------------------------------------------------------------------
// GN + ReLU apply (in place, fp32) — GN1 only
// ---------------------------------------------------------------------------
__global__ __launch_bounds__(256)
void gn_apply_relu(float* __restrict__ x, const float2* __restrict__ stats,
                   const float* __restrict__ sc, const float* __restrict__ bi,
                   int C, int Cpg) {
    long i = (long)blockIdx.x * 256 + threadIdx.x;
    long total4 = ((long)BATCH * C * PP) >> 2;
    if (i >= total4) return;
    long e = i << 2;
    int c = (int)((e >> 12) % C);
    int b = (int)(e / ((long)C * PP));
    float2 st = stats[b * 32 + c / Cpg];
    float a = st.y * sc[c];
    float bb = bi[c] - st.x * a;
    float4* p = (float4*)x;
    float4 v = p[i];
    v.x = fmaxf(v.x * a + bb, 0.f);
    v.y = fmaxf(v.y * a + bb, 0.f);
    v.z = fmaxf(v.z * a + bb, 0.f);
    v.w = fmaxf(v.w * a + bb, 0.f);
    p[i] = v;
}

// ---------------------------------------------------------------------------
__global__ __launch_bounds__(256)
void om_init(float* __restrict__ om, const float* __restrict__ boff) {
    int t = blockIdx.x * 256 + threadIdx.x;
    if (t < BATCH * 27 * PP) {
        int r = (t >> 12) % 27;
        om[t] = boff[r];
    }
}

// ---------------------------------------------------------------------------
// 3x3 offset conv (unchanged)
// ---------------------------------------------------------------------------
__global__ __launch_bounds__(256)
void conv_off_k(const float* __restrict__ out1, const float* __restrict__ w_off,
                float* __restrict__ om) {
    const int y0 = blockIdx.x * 4;
    const int c0 = blockIdx.y * 32;
    const int b = blockIdx.z;
    const int tid = threadIdx.x;
    const int tx = tid & 63, ty = tid >> 6;

    __shared__ __align__(16) float Aall[32 * 32 * 12];
    __shared__ float strip[6 * 64];

    for (int e = tid; e < 32 * 384; e += 256) {
        int c = e / 384;
        int rk = e % 384;
        int r = rk / 12, k = rk % 12;
        float v = 0.f;
        if (r < 27 && k < 9) v = w_off[((size_t)r * CB + (c0 + c)) * 9 + k];
        Aall[e] = v;
    }

    float acc[8][4];
#pragma unroll
    for (int i = 0; i < 8; i++)
#pragma unroll
        for (int j = 0; j < 4; j++) acc[i][j] = 0.f;

    for (int c = 0; c < 32; c++) {
        __syncthreads();
        for (int e = tid; e < 384; e += 256) {
            int r = e >> 6, col = e & 63;
            int gy = y0 + r - 1;
            strip[e] = (gy >= 0 && gy < 64)
                ? out1[(((size_t)b * CB + c0 + c) << 12) + (gy << 6) + col] : 0.f;
        }
        __syncthreads();
        float v[6][3];
#pragma unroll
        for (int r = 0; r < 6; r++)
#pragma unroll
            for (int d = 0; d < 3; d++) {
                int col = tx + d - 1;
                v[r][d] = (col >= 0 && col < 64) ? strip[r * 64 + col] : 0.f;
            }
        const float* Ac = &Aall[c * 384];
#pragma unroll
        for (int i = 0; i < 8; i++) {
            int m = ty + 4 * i;
            float4 w0 = *(const float4*)(Ac + m * 12);
            float4 w1v = *(const float4*)(Ac + m * 12 + 4);
            float w8 = Ac[m * 12 + 8];
            float wk[9] = {w0.x, w0.y, w0.z, w0.w, w1v.x, w1v.y, w1v.z, w1v.w, w8};
#pragma unroll
            for (int kk = 0; kk < 9; kk++) {
                int dy = kk / 3, dx = kk % 3;
#pragma unroll
                for (int j = 0; j < 4; j++)
                    acc[i][j] += wk[kk] * v[j + dy][dx];
            }
        }
    }
#pragma unroll
    for (int i = 0; i < 8; i++) {
        int m = ty + 4 * i;
        if (m < 27) {
#pragma unroll
            for (int j = 0; j < 4; j++) {
                int p = ((y0 + j) << 6) + tx;
                atomicAdd(&om[((size_t)b * 27 + m) * PP + p], acc[i][j]);
            }
        }
    }
}

// ---------------------------------------------------------------------------
// w2 fp32 [o][c][tap] -> bf16, K reordered: w2bf[o][tap*256 + c]
// ---------------------------------------------------------------------------
__global__ __launch_bounds__(256)
void w2conv(const float* __restrict__ w2, unsigned short* __restrict__ w2bf) {
    int t = blockIdx.x * 256 + threadIdx.x;
    if (t >= 256 * 2304) return;
    int o = t / 2304;
    int r = t - o * 2304;
    int tap = r >> 8, c = r & 255;
    w2bf[t] = f2bf(w2[((size_t)o * 256 + c) * 9 + tap]);
}

// ---------------------------------------------------------------------------
// Deformable einsum, bf16 MFMA. Bilinear corner/weight tables computed
// inline from om (each (b,k,p) belongs to exactly one block — no duplication).
// ---------------------------------------------------------------------------
__global__ __launch_bounds__(512)
void gemm2_mfma(const float* __restrict__ out1, const unsigned short* __restrict__ w2bf,
                const float* __restrict__ om, float* __restrict__ out2) {
    const int p0 = blockIdx.x * 64;
    const int b = blockIdx.z;
    const int tid = threadIdx.x;
    const int lane = tid & 63;
    const int wid = tid >> 6;          // 0..7
    const int l15 = lane & 15;
    const int quad = lane >> 4;        // 0..3

    __shared__ __align__(16) unsigned short As[256 * 40];
    __shared__ __align__(16) unsigned short Bs[64 * 40];
    __shared__ __align__(16) float swL[9 * 64 * 4];
    __shared__ __align__(16) int   siL[9 * 64 * 4];

    // inline samp_prep for this (b, p-tile)
    const float* ob = om + (size_t)b * 27 * PP;
    for (int e = tid; e < 576; e += 512) {
        int k = e >> 6, p = e & 63;
        int pg = p0 + p;
        float offx = ob[(size_t)k * PP + pg];
        float offy = ob[(size_t)(9 + k) * PP + pg];
        float ms = 1.f / (1.f + expf(-ob[(size_t)(18 + k) * PP + pg]));
        int y = pg >> 6, x = pg & 63;
        float py = (float)(y + k / 3 - 1) + offy;
        float px = (float)(x + (k % 3) - 1) + offx;
        float y0f = floorf(py), x0f = floorf(px);
        float wy1 = py - y0f, wx1 = px - x0f;
        int iy0 = (int)y0f, ix0 = (int)x0f;
        int iy1 = iy0 + 1, ix1 = ix0 + 1;
        bool vy0 = (iy0 >= 0 && iy0 < 64), vy1 = (iy1 >= 0 && iy1 < 64);
        bool vx0 = (ix0 >= 0 && ix0 < 64), vx1 = (ix1 >= 0 && ix1 < 64);
        int cy0 = min(max(iy0, 0), 63), cy1 = min(max(iy1, 0), 63);
        int cx0 = min(max(ix0, 0), 63), cx1 = min(max(ix1, 0), 63);
        swL[e * 4 + 0] = (vy0 && vx0) ? (1.f - wy1) * (1.f - wx1) * ms : 0.f;
        swL[e * 4 + 1] = (vy0 && vx1) ? (1.f - wy1) * wx1 * ms : 0.f;
        swL[e * 4 + 2] = (vy1 && vx0) ? wy1 * (1.f - wx1) * ms : 0.f;
        swL[e * 4 + 3] = (vy1 && vx1) ? wy1 * wx1 * ms : 0.f;
        siL[e * 4 + 0] = (cy0 << 6) + cx0;
        siL[e * 4 + 1] = (cy0 << 6) + cx1;
        siL[e * 4 + 2] = (cy1 << 6) + cx0;
        siL[e * 4 + 3] = (cy1 << 6) + cx1;
    }

    floatx4 acc[2][4];
#pragma unroll
    for (int i = 0; i < 2; i++)
#pragma unroll
        for (int j = 0; j < 4; j++) acc[i][j] = (floatx4){0.f, 0.f, 0.f, 0.f};

    const int bp = tid & 63;
    const int bcq = tid >> 6;
    const int so = tid >> 1;
    const int sh = tid & 1;

    __syncthreads();   // tables ready

    const int mbase = wid * 32;

    for (int tap = 0; tap < 9; tap++) {
        floatx4 wv = *(const floatx4*)&swL[(tap * 64 + bp) * 4];
        intx4 iv = *(const intx4*)&siL[(tap * 64 + bp) * 4];
        for (int cc = 0; cc < 8; cc++) {
            const int c0 = cc * 32;
            // stage A tile (full 32-channel row: 2x float4 per thread)
            {
                const unsigned short* gsrc =
                    w2bf + (size_t)so * 2304 + tap * 256 + c0 + sh * 16;
                float4 v0 = *(const float4*)gsrc;
                float4 v1 = *(const float4*)(gsrc + 8);
                *(float4*)((char*)As + so * 80 + sh * 32) = v0;
                *(float4*)((char*)As + so * 80 + sh * 32 + 16) = v1;
            }
            // build B tile: 4 channels for pixel bp
            {
                const float* rowb = out1 + (((size_t)b * CB + c0 + bcq * 4) << 12);
                unsigned short bv[4];
#pragma unroll
                for (int s = 0; s < 4; s++) {
                    const float* row = rowb + ((size_t)s << 12);
                    float v = wv[0] * row[iv[0]] + wv[1] * row[iv[1]] +
                              wv[2] * row[iv[2]] + wv[3] * row[iv[3]];
                    bv[s] = f2bf(v);
                }
                *(ushort4*)((char*)Bs + bp * 80 + bcq * 8) =
                    make_ushort4(bv[0], bv[1], bv[2], bv[3]);
            }
            __syncthreads();
            shortx8 af[2], bf[4];
#pragma unroll
            for (int i = 0; i < 2; i++)
                af[i] = *(const shortx8*)((const char*)As +
                        (mbase + 16 * i + l15) * 80 + quad * 16);
#pragma unroll
            for (int j = 0; j < 4; j++)
                bf[j] = *(const shortx8*)((const char*)Bs +
                        (16 * j + l15) * 80 + quad * 16);
#pragma unroll
            for (int i = 0; i < 2; i++)
#pragma unroll
                for (int j = 0; j < 4; j++)
                    acc[i][j] = __builtin_amdgcn_mfma_f32_16x16x32_bf16(
                        af[i], bf[j], acc[i][j], 0, 0, 0);
            __syncthreads();
        }
    }

#pragma unroll
    for (int i = 0; i < 2; i++) {
#pragma unroll
        for (int r = 0; r < 4; r++) {
            int row = mbase + 16 * i + quad * 4 + r;
            float* dst = out2 + (((size_t)b * CB + row) << 12) + p0 + l15;
#pragma unroll
            for (int j = 0; j < 4; j++)
                dst[16 * j] = acc[i][j][r];
        }
    }
}

// ---------------------------------------------------------------------------
// Final: relu(gn3(d_out)*sc+bi + x) in place.
// ---------------------------------------------------------------------------
__global__ __launch_bounds__(256)
void final_k(float* __restrict__ dout, const float* __restrict__ x,
             const float2* __restrict__ stats, const float* __restrict__ sc,
             const float* __restrict__ bi) {
    long i = (long)blockIdx.x * 256 + threadIdx.x;
    long total4 = ((long)BATCH * CIN * PP) >> 2;
    if (i >= total4) return;
    long e = i << 2;
    int c = (int)((e >> 12) & 1023);
    int b = (int)(e >> 22);
    float2 st = stats[b * 32 + (c >> 5)];
    float a = st.y * sc[c];
    float bb = bi[c] - st.x * a;
    float4 v = ((float4*)dout)[i];
    float4 xv = ((const float4*)x)[i];
    v.x = fmaxf(v.x * a + bb + xv.x, 0.f);
    v.y = fmaxf(v.y * a + bb + xv.y, 0.f);
    v.z = fmaxf(v.z * a + bb + xv.z, 0.f);
    v.w = fmaxf(v.w * a + bb + xv.w, 0.f);
    ((float4*)dout)[i] = v;
}

// ---------------------------------------------------------------------------
// Workspace layout (float offsets). xbfT (33.5 MB) aliases out2/om/w2bf/
// out2bfT/w3bf/st — all only written AFTER conv1 has consumed xbfT.
//   W1BF   0          (262144 shorts)
//   OUT1   131072
//   XBFT   4325376    (16777216 shorts, spans to 12713984)  [alias region:]
//   OUT2   4325376
//   OM     8519680
//   W2BF   8962048    (589824 shorts)
//   OUT2BT 9256960    (4194304 shorts)
//   W3BF   11354112   (262144 shorts)
//   ST     11485184   (3 x 128 float2)
// total = 12713984 floats = 50.9 MB
// ---------------------------------------------------------------------------
extern "C" void kernel_launch(void* const* d_in, const int* in_sizes, int n_in,
                              void* d_out, int out_size, void* d_ws, size_t ws_size,
                              hipStream_t stream) {
    const float* x   = (const float*)d_in[0];
    const float* w1  = (const float*)d_in[1];
    const float* g1s = (const float*)d_in[2];
    const float* g1b = (const float*)d_in[3];
    const float* wof = (const float*)d_in[4];
    const float* bof = (const float*)d_in[5];
    const float* w2  = (const float*)d_in[6];
    const float* g2s = (const float*)d_in[7];
    const float* g2b = (const float*)d_in[8];
    const float* w3  = (const float*)d_in[9];
    const float* g3s = (const float*)d_in[10];
    const float* g3b = (const float*)d_in[11];
    float* out = (float*)d_out;

    float* ws = (float*)d_ws;
    unsigned short* w1bf   = (unsigned short*)(ws + 0);
    float*          out1   = ws + 131072;
    unsigned short* xbfT   = (unsigned short*)(ws + 4325376);
    float*          out2   = ws + 4325376;
    float*          om     = ws + 8519680;
    unsigned short* w2bf   = (unsigned short*)(ws + 8962048);
    unsigned short* out2bT = (unsigned short*)(ws + 9256960);
    unsigned short* w3bf   = (unsigned short*)(ws + 11354112);
    float2* st1 = (float2*)(ws + 11485184);
    float2* st2 = st1 + 128;
    float2* st3 = st2 + 128;

    // x [b][1024][4096] -> xbfT [b][4096][1024] bf16
    transp_bf16<<<dim3(64, 16, 4), 256, 0, stream>>>(x, xbfT, 1024, 4096);
    cvt_bf16<<<1024, 256, 0, stream>>>(w1, w1bf, 262144);
    // conv1: out1[b][256][4096] = w1bf @ xbfT
    gemm_bf16<<<dim3(32, 2, 4), 256, 0, stream>>>(w1bf, xbfT, out1, 256, 4096, 1024);
    gn_stats<<<128, 256, 0, stream>>>(out1, st1, 256, 8);
    gn_apply_relu<<<4096, 256, 0, stream>>>(out1, st1, g1s, g1b, 256, 8);
    // offset conv
    om_init<<<1728, 256, 0, stream>>>(om, bof);
    conv_off_k<<<dim3(16, 8, 4), 256, 0, stream>>>(out1, wof, om);
    // weight conversions (after conv1: w2bf/w3bf live inside xbfT alias region)
    w2conv<<<2304, 256, 0, stream>>>(w2, w2bf);
    cvt_bf16<<<1024, 256, 0, stream>>>(w3, w3bf, 262144);
    // deformable einsum (inline bilinear tables from om)
    gemm2_mfma<<<dim3(64, 1, 4), 512, 0, stream>>>(out1, w2bf, om, out2);
    // GN2 stats, then fused apply+relu+transpose-convert -> out2bT
    gn_stats<<<128, 256, 0, stream>>>(out2, st2, 256, 8);
    gn2t<<<dim3(64, 4, 4), 256, 0, stream>>>(out2, st2, g2s, g2b, out2bT);
    // conv3: out[b][1024][4096] = w3bf @ out2bT
    gemm_bf16<<<dim3(32, 8, 4), 256, 0, stream>>>(w3bf, out2bT, out, 1024, 4096, 256);
    gn_stats<<<128, 256, 0, stream>>>(out, st3, 1024, 32);
    final_k<<<16384, 256, 0, stream>>>(out, x, st3, g3s, g3b);
}